// Round 5
// baseline (158.744 us; speedup 1.0000x reference)
//
#include <hip/hip_runtime.h>
#include <hip/hip_bf16.h>
#include <float.h>
#include <math.h>

// Problem constants
#define BATCH   8192
#define NCH     45
#define SEQL    21
#define NEXP    22
#define ROWLEN  945          // NCH*SEQL
#define GOFF    7741440      // BATCH*ROWLEN, start of A_flat in d_out

#define K1_BLOCKS 1024       // 8 batches per block
#define K3_BLOCKS 2048       // 4 batches per block (3780 floats = 945 float4 exactly)

__device__ __forceinline__ float fast_tanh(float v) {
    const float t = __expf(2.f * v);
    return (t - 1.f) / (t + 1.f);
}

// ---------------- K1: gating (conv -> max/avg pool -> 2x MLP -> softmax) ----------------
__global__ __launch_bounds__(256) void k1_gate(
    const float* __restrict__ x,
    const float* __restrict__ gc_w, const float* __restrict__ gc_b,
    const float* __restrict__ w1,   const float* __restrict__ b1,
    const float* __restrict__ w2,   const float* __restrict__ b2,
    float* __restrict__ gate_out,   float* __restrict__ partialsT)
{
    __shared__ float xsh[8 * ROWLEN];       // 30240 B, 8 batch rows
    __shared__ float buf45a[4][45];
    __shared__ float buf45b[4][45];
    __shared__ float buf25a[4][25];
    __shared__ float buf25b[4][25];
    __shared__ float part[4][45];

    const int tid  = threadIdx.x;
    const int w    = tid >> 6;
    const int lane = tid & 63;
    const int b_base = blockIdx.x * 8;

    // ---- stage 8 consecutive batch rows, fully coalesced float4 ----
    {
        const float4* x4 = (const float4*)(x + (size_t)b_base * ROWLEN); // 30240B-aligned
        float4* xsh4 = (float4*)xsh;
        for (int q = tid; q < 1890; q += 256) xsh4[q] = x4[q];
    }
    __syncthreads();

    float acc = 0.f;   // per-lane (channel) gate accumulator over this wave's batches

    for (int iter = 0; iter < 2; ++iter) {
        const int bb = w * 2 + iter;        // local row 0..7
        const int b  = b_base + bb;
        float g = 0.f;
        if (lane < NCH) {
            // conv: temp[o] = gc_b[o] + sum_l gc_w[o,l]*x[b,lane,l]; pool over o
            float xr[SEQL];
            const float* xp = &xsh[bb * ROWLEN + lane * SEQL];  // stride-21: <=2-way, free
            #pragma unroll
            for (int l = 0; l < SEQL; ++l) xr[l] = xp[l];
            float mx = -FLT_MAX, av = 0.f;
            for (int o = 0; o < SEQL; ++o) {
                float t = gc_b[o];
                #pragma unroll
                for (int l = 0; l < SEQL; ++l) t = fmaf(gc_w[o * SEQL + l], xr[l], t);
                mx = fmaxf(mx, t);
                av += t;
            }
            av *= (1.f / 21.f);
            buf45a[w][lane] = mx;
            buf45b[w][lane] = av;
        }
        __syncthreads();
        if (lane < 25) {   // layer 1 (shared weights, two inputs mx/av)
            float tm = b1[lane], ta = b1[lane];
            for (int i = 0; i < NCH; ++i) {
                const float wv = w1[lane * NCH + i];
                tm = fmaf(wv, buf45a[w][i], tm);
                ta = fmaf(wv, buf45b[w][i], ta);
            }
            buf25a[w][lane] = fast_tanh(tm);
            buf25b[w][lane] = fast_tanh(ta);
        }
        __syncthreads();
        if (lane < NCH) {  // layer 2 + combine; exp without max (g in [-2,2], safe)
            float tm = b2[lane], ta = b2[lane];
            for (int j = 0; j < 25; ++j) {
                const float wv = w2[lane * 25 + j];
                tm = fmaf(wv, buf25a[w][j], tm);
                ta = fmaf(wv, buf25b[w][j], ta);
            }
            g = __expf(fast_tanh(tm) + fast_tanh(ta));
            buf45a[w][lane] = g;
        }
        __syncthreads();
        if (lane < NCH) {
            float s = 0.f;
            for (int i = 0; i < NCH; ++i) s += buf45a[w][i];
            const float gt = g / s;
            gate_out[(size_t)b * NCH + lane] = gt;
            acc += gt;
        }
        __syncthreads();   // protect LDS reuse next iteration
    }

    if (lane < NCH) part[w][lane] = acc;
    __syncthreads();
    if (tid < NCH) {
        // transposed: channel-major so K2 block c reads a contiguous 4KB row
        partialsT[tid * K1_BLOCKS + blockIdx.x] =
            part[0][tid] + part[1][tid] + part[2][tid] + part[3][tid];
    }
}

// ---------------- K2: 46 blocks — per-channel reduce (0..44) + expert scalars (45) -------
__global__ __launch_bounds__(256) void k2_reduce(
    const float* __restrict__ partialsT,
    const float* __restrict__ wq, const float* __restrict__ bq,
    const float* __restrict__ wk, const float* __restrict__ bk,
    const float* __restrict__ wv, const float* __restrict__ bv,
    const float* __restrict__ wo, const float* __restrict__ bo,
    float* __restrict__ mg, float* __restrict__ escal)
{
    const int tid = threadIdx.x;
    const int c   = blockIdx.x;

    if (c < NCH) {
        // 256 threads x one float4 = all 1024 partials of channel c (contiguous)
        __shared__ float wsum[4];
        const float4 v = ((const float4*)(partialsT + c * K1_BLOCKS))[tid];
        float s = (v.x + v.y) + (v.z + v.w);
        #pragma unroll
        for (int off = 32; off > 0; off >>= 1) s += __shfl_xor(s, off, 64);
        if ((tid & 63) == 0) wsum[tid >> 6] = s;
        __syncthreads();
        if (tid == 0) mg[c] = (wsum[0] + wsum[1]) + (wsum[2] + wsum[3]);
    } else {
        if (tid < NEXP) {    // per-expert scalars (independent of selection)
            const int e = tid;
            float A = 0.f, Cc = 0.f, P = 0.f, Q = 0.f;
            for (int i = 0; i < SEQL; ++i) {
                A  = fmaf(wq[e * SEQL + i], wk[e * SEQL + i], A);
                Cc = fmaf(bq[e * SEQL + i], wk[e * SEQL + i], Cc);
                P  = fmaf(wo[e * SEQL + i], wv[e * SEQL + i], P);
                Q  = fmaf(wo[e * SEQL + i], bv[e * SEQL + i], Q);
            }
            Q += bo[e];
            escal[e] = A; escal[22 + e] = Cc; escal[44 + e] = P; escal[66 + e] = Q;
        }
    }
}

// ---------------- K3: ballot top-k + register-resident per-(b,e) softmax + float4 I/O ----
__global__ __launch_bounds__(256) void k3_attn(
    const float* __restrict__ x, const float* __restrict__ gate,
    const float* __restrict__ mg, const float* __restrict__ escal,
    float* __restrict__ out)
{
    __shared__ float xsh[4 * ROWLEN];   // 15120 B: 4 batch rows of x
    __shared__ float ash[4 * ROWLEN];   // 15120 B: full A image incl. zeros
    __shared__ float smg[64];
    __shared__ float gat[4][NEXP];
    __shared__ float sA[NEXP], sC[NEXP], sP[NEXP], sQ[NEXP];
    __shared__ int   ssel[NEXP];

    const int tid = threadIdx.x;

    if (tid < 64) smg[tid] = (tid < NCH) ? mg[tid] : -FLT_MAX;
    if (tid >= 64 && tid < 64 + NEXP) {
        const int e = tid - 64;
        sA[e] = escal[e];       sC[e] = escal[22 + e];
        sP[e] = escal[44 + e];  sQ[e] = escal[66 + e];
    }

    const int b0 = blockIdx.x * 4;
    // stage 4 rows of x (945 float4, coalesced) + zero the A image
    {
        const float4* x4 = (const float4*)x + (size_t)blockIdx.x * 945;
        float4* xsh4 = (float4*)xsh;
        float4* ash4 = (float4*)ash;
        const float4 z = make_float4(0.f, 0.f, 0.f, 0.f);
        for (int q = tid; q < 945; q += 256) {
            xsh4[q] = x4[q];
            ash4[q] = z;
        }
    }
    __syncthreads();

    // wave-0 ballot top-22: rank channel t among 45 (ties -> lower index wins)
    if (tid < 64) {
        const float v = smg[tid];
        int rank = 0;
        #pragma unroll
        for (int i = 0; i < NCH; ++i) {
            const float u = smg[i];
            rank += (u > v || (u == v && i < tid)) ? 1 : 0;
        }
        const bool seld = (tid < NCH) && (rank < NEXP);
        const unsigned long long m = __ballot(seld);
        if (seld) {
            const int e = __popcll(m & ((1ull << tid) - 1ull));
            ssel[e] = tid;
        }
    }
    __syncthreads();

    if (tid < 4 * NEXP) {               // gates for 4 batches x 22 selected channels
        const int bi = tid / NEXP, e = tid - bi * NEXP;
        gat[bi][e] = gate[(size_t)(b0 + bi) * NCH + ssel[e]];
    }
    __syncthreads();

    // compute: one thread per (batch, expert, half) = 4*22*2 = 176 tasks.
    // Row xr[21] loaded from LDS ONCE (21 reads vs 441 in the per-l layout),
    // then 10-11 softmax rows computed serially in registers.
    if (tid < 176) {
        const int bi = tid / 44;
        const int r  = tid - bi * 44;
        const int e  = r >> 1;
        const int h  = r & 1;
        const int l_lo = h ? 11 : 0;
        const int l_hi = h ? 21 : 11;

        float xr[SEQL];
        {
            const float* xp = &xsh[bi * ROWLEN + ssel[e] * SEQL];
            #pragma unroll
            for (int m = 0; m < SEQL; ++m) xr[m] = xp[m];
        }
        const float Ae = sA[e], Ce = sC[e], Pe = sP[e], Qe = sQ[e];
        const float ge = gat[bi][e];
        float* ap = &ash[bi * ROWLEN + ssel[e] * SEQL];

        for (int l = l_lo; l < l_hi; ++l) {
            const float alpha = fmaf(Ae, xr[l], Ce);
            float den = 0.f, num = 0.f;
            #pragma unroll
            for (int m = 0; m < SEQL; ++m) {
                const float wgt = __expf(alpha * xr[m]);
                den += wgt;
                num = fmaf(xr[m], wgt, num);
            }
            ap[l] = fmaf(Pe, num / den, Qe) * ge;
        }
    }
    __syncthreads();

    // coalesced float4 writes: G = A .* x, then A
    {
        const float4* xsh4 = (const float4*)xsh;
        const float4* ash4 = (const float4*)ash;
        float4* g4 = (float4*)out + (size_t)blockIdx.x * 945;
        float4* a4 = (float4*)(out + (size_t)GOFF) + (size_t)blockIdx.x * 945;
        for (int q = tid; q < 945; q += 256) {
            const float4 a = ash4[q];
            const float4 xv = xsh4[q];
            g4[q] = make_float4(a.x * xv.x, a.y * xv.y, a.z * xv.z, a.w * xv.w);
            a4[q] = a;
        }
    }
}

extern "C" void kernel_launch(void* const* d_in, const int* in_sizes, int n_in,
                              void* d_out, int out_size, void* d_ws, size_t ws_size,
                              hipStream_t stream)
{
    const float* x    = (const float*)d_in[0];
    const float* gc_w = (const float*)d_in[1];
    const float* gc_b = (const float*)d_in[2];
    const float* w1   = (const float*)d_in[3];
    const float* b1   = (const float*)d_in[4];
    const float* w2   = (const float*)d_in[5];
    const float* b2   = (const float*)d_in[6];
    const float* wq   = (const float*)d_in[7];
    const float* bq   = (const float*)d_in[8];
    const float* wk   = (const float*)d_in[9];
    const float* bk   = (const float*)d_in[10];
    const float* wv   = (const float*)d_in[11];
    const float* bv   = (const float*)d_in[12];
    const float* wo   = (const float*)d_in[13];
    const float* bo   = (const float*)d_in[14];

    float* ws        = (float*)d_ws;
    float* gateBuf   = ws;                       // BATCH*45 = 368640 floats
    float* partialsT = ws + 368640;              // 45*1024  = 46080 floats (channel-major)
    float* mg        = ws + 414720;              // 45 floats (pad to 64)
    float* escal     = ws + 414784;              // 88 floats (A,C,P,Q per expert)
    float* outF      = (float*)d_out;

    k1_gate<<<dim3(K1_BLOCKS), dim3(256), 0, stream>>>(x, gc_w, gc_b, w1, b1, w2, b2,
                                                       gateBuf, partialsT);
    k2_reduce<<<dim3(46), dim3(256), 0, stream>>>(partialsT, wq, bq, wk, bk, wv, bv,
                                                  wo, bo, mg, escal);
    k3_attn<<<dim3(K3_BLOCKS), dim3(256), 0, stream>>>(x, gateBuf, mg, escal, outF);
}

// Round 6
// 152.169 us; speedup vs baseline: 1.0432x; 1.0432x over previous
//
#include <hip/hip_runtime.h>
#include <hip/hip_bf16.h>
#include <float.h>
#include <math.h>

// Problem constants
#define BATCH   8192
#define NCH     45
#define SEQL    21
#define NEXP    22
#define ROWLEN  945          // NCH*SEQL
#define GOFF    7741440      // BATCH*ROWLEN, start of A_flat in d_out

#define K1_BLOCKS 1024       // 8 batches per block
#define K3_BLOCKS 2048       // 4 batches per block (3780 floats = 945 float4 exactly)

__device__ __forceinline__ float fast_tanh(float v) {
    const float t = __expf(2.f * v);
    return (t - 1.f) / (t + 1.f);
}

// ---------------- K1: gating (conv -> max/avg pool -> 2x MLP -> softmax) ----------------
__global__ __launch_bounds__(256) void k1_gate(
    const float* __restrict__ x,
    const float* __restrict__ gc_w, const float* __restrict__ gc_b,
    const float* __restrict__ w1,   const float* __restrict__ b1,
    const float* __restrict__ w2,   const float* __restrict__ b2,
    float* __restrict__ gate_out,   float* __restrict__ partialsT)
{
    __shared__ float xsh[8 * ROWLEN];       // 30240 B, 8 batch rows
    __shared__ float buf45a[4][45];
    __shared__ float buf45b[4][45];
    __shared__ float buf25a[4][25];
    __shared__ float buf25b[4][25];
    __shared__ float part[4][45];

    const int tid  = threadIdx.x;
    const int w    = tid >> 6;
    const int lane = tid & 63;
    const int b_base = blockIdx.x * 8;

    // ---- stage 8 consecutive batch rows, fully coalesced float4 ----
    {
        const float4* x4 = (const float4*)(x + (size_t)b_base * ROWLEN); // 30240B-aligned
        float4* xsh4 = (float4*)xsh;
        for (int q = tid; q < 1890; q += 256) xsh4[q] = x4[q];
    }
    __syncthreads();

    float acc = 0.f;   // per-lane (channel) gate accumulator over this wave's batches

    for (int iter = 0; iter < 2; ++iter) {
        const int bb = w * 2 + iter;        // local row 0..7
        const int b  = b_base + bb;
        float g = 0.f;
        if (lane < NCH) {
            // conv: temp[o] = gc_b[o] + sum_l gc_w[o,l]*x[b,lane,l]; pool over o
            float xr[SEQL];
            const float* xp = &xsh[bb * ROWLEN + lane * SEQL];  // stride-21: <=2-way, free
            #pragma unroll
            for (int l = 0; l < SEQL; ++l) xr[l] = xp[l];
            float mx = -FLT_MAX, av = 0.f;
            for (int o = 0; o < SEQL; ++o) {
                float t = gc_b[o];
                #pragma unroll
                for (int l = 0; l < SEQL; ++l) t = fmaf(gc_w[o * SEQL + l], xr[l], t);
                mx = fmaxf(mx, t);
                av += t;
            }
            av *= (1.f / 21.f);
            buf45a[w][lane] = mx;
            buf45b[w][lane] = av;
        }
        __syncthreads();
        if (lane < 25) {   // layer 1 (shared weights, two inputs mx/av)
            float tm = b1[lane], ta = b1[lane];
            for (int i = 0; i < NCH; ++i) {
                const float wv = w1[lane * NCH + i];
                tm = fmaf(wv, buf45a[w][i], tm);
                ta = fmaf(wv, buf45b[w][i], ta);
            }
            buf25a[w][lane] = fast_tanh(tm);
            buf25b[w][lane] = fast_tanh(ta);
        }
        __syncthreads();
        if (lane < NCH) {  // layer 2 + combine; exp without max (g in [-2,2], safe)
            float tm = b2[lane], ta = b2[lane];
            for (int j = 0; j < 25; ++j) {
                const float wv = w2[lane * 25 + j];
                tm = fmaf(wv, buf25a[w][j], tm);
                ta = fmaf(wv, buf25b[w][j], ta);
            }
            g = __expf(fast_tanh(tm) + fast_tanh(ta));
            buf45a[w][lane] = g;
        }
        __syncthreads();
        if (lane < NCH) {
            float s = 0.f;
            for (int i = 0; i < NCH; ++i) s += buf45a[w][i];
            const float gt = g / s;
            gate_out[(size_t)b * NCH + lane] = gt;
            acc += gt;
        }
        __syncthreads();   // protect LDS reuse next iteration
    }

    if (lane < NCH) part[w][lane] = acc;
    __syncthreads();
    if (tid < NCH) {
        // transposed: channel-major so K2 block c reads a contiguous 4KB row
        partialsT[tid * K1_BLOCKS + blockIdx.x] =
            part[0][tid] + part[1][tid] + part[2][tid] + part[3][tid];
    }
}

// ---------------- K2: 46 blocks — per-channel reduce (0..44) + expert scalars (45) -------
__global__ __launch_bounds__(256) void k2_reduce(
    const float* __restrict__ partialsT,
    const float* __restrict__ wq, const float* __restrict__ bq,
    const float* __restrict__ wk, const float* __restrict__ bk,
    const float* __restrict__ wv, const float* __restrict__ bv,
    const float* __restrict__ wo, const float* __restrict__ bo,
    float* __restrict__ mg, float* __restrict__ escal)
{
    const int tid = threadIdx.x;
    const int c   = blockIdx.x;

    if (c < NCH) {
        // 256 threads x one float4 = all 1024 partials of channel c (contiguous)
        __shared__ float wsum[4];
        const float4 v = ((const float4*)(partialsT + c * K1_BLOCKS))[tid];
        float s = (v.x + v.y) + (v.z + v.w);
        #pragma unroll
        for (int off = 32; off > 0; off >>= 1) s += __shfl_xor(s, off, 64);
        if ((tid & 63) == 0) wsum[tid >> 6] = s;
        __syncthreads();
        if (tid == 0) mg[c] = (wsum[0] + wsum[1]) + (wsum[2] + wsum[3]);
    } else {
        if (tid < NEXP) {    // per-expert scalars (independent of selection)
            const int e = tid;
            float A = 0.f, Cc = 0.f, P = 0.f, Q = 0.f;
            for (int i = 0; i < SEQL; ++i) {
                A  = fmaf(wq[e * SEQL + i], wk[e * SEQL + i], A);
                Cc = fmaf(bq[e * SEQL + i], wk[e * SEQL + i], Cc);
                P  = fmaf(wo[e * SEQL + i], wv[e * SEQL + i], P);
                Q  = fmaf(wo[e * SEQL + i], bv[e * SEQL + i], Q);
            }
            Q += bo[e];
            escal[e] = A; escal[22 + e] = Cc; escal[44 + e] = P; escal[66 + e] = Q;
        }
    }
}

// ---------------- K3: ballot top-k + full-packed register-row softmax + float4 I/O -------
__global__ __launch_bounds__(256) void k3_attn(
    const float* __restrict__ x, const float* __restrict__ gate,
    const float* __restrict__ mg, const float* __restrict__ escal,
    float* __restrict__ out)
{
    __shared__ float xsh[4 * ROWLEN];   // 15120 B: 4 batch rows of x
    __shared__ float ash[4 * ROWLEN];   // 15120 B: full A image incl. zeros
    __shared__ float smg[64];
    __shared__ float gat[4][NEXP];
    __shared__ float sA[NEXP], sC[NEXP], sP[NEXP], sQ[NEXP];
    __shared__ int   ssel[NEXP];

    const int tid = threadIdx.x;

    if (tid < 64) smg[tid] = (tid < NCH) ? mg[tid] : -FLT_MAX;
    if (tid >= 64 && tid < 64 + NEXP) {
        const int e = tid - 64;
        sA[e] = escal[e];       sC[e] = escal[22 + e];
        sP[e] = escal[44 + e];  sQ[e] = escal[66 + e];
    }

    const int b0 = blockIdx.x * 4;
    // stage 4 rows of x (945 float4, coalesced) + zero the A image
    {
        const float4* x4 = (const float4*)x + (size_t)blockIdx.x * 945;
        float4* xsh4 = (float4*)xsh;
        float4* ash4 = (float4*)ash;
        const float4 z = make_float4(0.f, 0.f, 0.f, 0.f);
        for (int q = tid; q < 945; q += 256) {
            xsh4[q] = x4[q];
            ash4[q] = z;
        }
    }
    __syncthreads();

    // wave-0 ballot top-22: rank channel t among 45 (ties -> lower index wins)
    if (tid < 64) {
        const float v = smg[tid];
        int rank = 0;
        #pragma unroll
        for (int i = 0; i < NCH; ++i) {
            const float u = smg[i];
            rank += (u > v || (u == v && i < tid)) ? 1 : 0;
        }
        const bool seld = (tid < NCH) && (rank < NEXP);
        const unsigned long long m = __ballot(seld);
        if (seld) {
            const int e = __popcll(m & ((1ull << tid) - 1ull));
            ssel[e] = tid;
        }
    }
    __syncthreads();

    if (tid < 4 * NEXP) {               // gates for 4 batches x 22 selected channels
        const int bi = tid / NEXP, e = tid - bi * NEXP;
        gat[bi][e] = gate[(size_t)(b0 + bi) * NCH + ssel[e]];
    }
    __syncthreads();

    // Full-packed compute: thread t owns contiguous l-task range
    // [t*1848/256, (t+1)*1848/256) -> 7-8 tasks spanning at most 2 (b,e) rows.
    // Row cached in registers (m-loop fully unrolled, static indices only).
    {
        const int t0 = (tid * 1848) >> 8;
        const int t1 = ((tid + 1) * 1848) >> 8;
        int cur_be = -1;
        float xr[SEQL];
        float Ae = 0.f, Ce = 0.f, Pe = 0.f, Qe = 0.f, ge = 0.f;
        const float* xp = nullptr;
        float* ap = nullptr;

        for (int tsk = t0; tsk < t1; ++tsk) {
            const int be = (tsk * 3121) >> 16;          // tsk/21, exact for tsk<1848
            if (be != cur_be) {
                cur_be = be;
                const int bi = (be * 2979) >> 16;       // be/22, exact for be<88
                const int e  = be - bi * NEXP;
                xp = &xsh[bi * ROWLEN + ssel[e] * SEQL];
                ap = &ash[bi * ROWLEN + ssel[e] * SEQL];
                #pragma unroll
                for (int m = 0; m < SEQL; ++m) xr[m] = xp[m];
                Ae = sA[e]; Ce = sC[e]; Pe = sP[e]; Qe = sQ[e];
                ge = gat[bi][e];
            }
            const int l = tsk - cur_be * SEQL;
            const float alpha = fmaf(Ae, xp[l], Ce);    // LDS read avoids dyn reg-index
            float den = 0.f, num = 0.f;
            #pragma unroll
            for (int m = 0; m < SEQL; ++m) {
                const float wgt = __expf(alpha * xr[m]);
                den += wgt;
                num = fmaf(xr[m], wgt, num);
            }
            ap[l] = fmaf(Pe, num / den, Qe) * ge;
        }
    }
    __syncthreads();

    // coalesced float4 writes: G = A .* x, then A
    {
        const float4* xsh4 = (const float4*)xsh;
        const float4* ash4 = (const float4*)ash;
        float4* g4 = (float4*)out + (size_t)blockIdx.x * 945;
        float4* a4 = (float4*)(out + (size_t)GOFF) + (size_t)blockIdx.x * 945;
        for (int q = tid; q < 945; q += 256) {
            const float4 a = ash4[q];
            const float4 xv = xsh4[q];
            g4[q] = make_float4(a.x * xv.x, a.y * xv.y, a.z * xv.z, a.w * xv.w);
            a4[q] = a;
        }
    }
}

extern "C" void kernel_launch(void* const* d_in, const int* in_sizes, int n_in,
                              void* d_out, int out_size, void* d_ws, size_t ws_size,
                              hipStream_t stream)
{
    const float* x    = (const float*)d_in[0];
    const float* gc_w = (const float*)d_in[1];
    const float* gc_b = (const float*)d_in[2];
    const float* w1   = (const float*)d_in[3];
    const float* b1   = (const float*)d_in[4];
    const float* w2   = (const float*)d_in[5];
    const float* b2   = (const float*)d_in[6];
    const float* wq   = (const float*)d_in[7];
    const float* bq   = (const float*)d_in[8];
    const float* wk   = (const float*)d_in[9];
    const float* bk   = (const float*)d_in[10];
    const float* wv   = (const float*)d_in[11];
    const float* bv   = (const float*)d_in[12];
    const float* wo   = (const float*)d_in[13];
    const float* bo   = (const float*)d_in[14];

    float* ws        = (float*)d_ws;
    float* gateBuf   = ws;                       // BATCH*45 = 368640 floats
    float* partialsT = ws + 368640;              // 45*1024  = 46080 floats (channel-major)
    float* mg        = ws + 414720;              // 45 floats (pad to 64)
    float* escal     = ws + 414784;              // 88 floats (A,C,P,Q per expert)
    float* outF      = (float*)d_out;

    k1_gate<<<dim3(K1_BLOCKS), dim3(256), 0, stream>>>(x, gc_w, gc_b, w1, b1, w2, b2,
                                                       gateBuf, partialsT);
    k2_reduce<<<dim3(46), dim3(256), 0, stream>>>(partialsT, wq, bq, wk, bk, wv, bv,
                                                  wo, bo, mg, escal);
    k3_attn<<<dim3(K3_BLOCKS), dim3(256), 0, stream>>>(x, gateBuf, mg, escal, outF);
}